// Round 9
// baseline (340.237 us; speedup 1.0000x reference)
//
#include <hip/hip_runtime.h>
#include <hip/hip_bf16.h>

typedef unsigned short ushort_t;
typedef unsigned int uint_t;

typedef __attribute__((ext_vector_type(8))) short bf8;
typedef __attribute__((ext_vector_type(4))) float f4;
typedef __attribute__((ext_vector_type(16))) float f16v;

__device__ __forceinline__ float bf2f(ushort_t u) {
    unsigned int x = ((unsigned int)u) << 16;
    return __uint_as_float(x);
}
__device__ __forceinline__ ushort_t f2bf(float f) {
    unsigned int x = __float_as_uint(f);
    unsigned int r = x + 0x7fffu + ((x >> 16) & 1u);
    return (ushort_t)(r >> 16);
}
__device__ __forceinline__ uint_t pack2bf(float a, float b) {
    return (uint_t)f2bf(a) | ((uint_t)f2bf(b) << 16);
}
// fast pack: round-half-up + v_perm_b32 byte gather (3 VALU vs ~9)
__device__ __forceinline__ uint_t pack2bf_fast(float a, float b) {
    uint_t au = __float_as_uint(a) + 0x8000u;
    uint_t bu = __float_as_uint(b) + 0x8000u;
    return __builtin_amdgcn_perm(bu, au, 0x07060302);  // lo16=a_hi, hi16=b_hi
}
// v_exp_f32 computes 2^x directly (inputs pre-scaled by log2e at QKV time)
__device__ __forceinline__ float exp2_fast(float x) {
    float r; asm("v_exp_f32 %0, %1" : "=v"(r) : "v"(x)); return r;
}
// 2 f32 -> packed bf16 (RTNE), 1 instr vs 3
__device__ __forceinline__ uint_t cvtpk_bf16(float lo, float hi) {
    uint_t r; asm("v_cvt_pk_bf16_f32 %0, %1, %2" : "=v"(r) : "v"(lo), "v"(hi)); return r;
}
// after: a = [a.lo32, b.lo32], b = [a.hi32, b.hi32]
__device__ __forceinline__ void pl32swap(uint_t &a, uint_t &b) {
    asm("v_permlane32_swap_b32 %0, %1" : "+v"(a), "+v"(b));
}

__device__ __forceinline__ void gl2lds16(const ushort_t* g, ushort_t* l) {
    __builtin_amdgcn_global_load_lds(
        (const __attribute__((address_space(1))) void*)g,
        (__attribute__((address_space(3))) void*)l, 16, 0, 0);
}

__device__ __forceinline__ void waitl0() {
    asm volatile("s_waitcnt lgkmcnt(0)" ::: "memory");
    __builtin_amdgcn_sched_barrier(0);
}

// ---------------------------------------------------------------------------
// prep (merged): [0,4096) x fp32->bf16; [4096,4224) Wg pack; [4224,8320)
// weight transpose-convert (4 matrices, 32x32 tiles)
// ---------------------------------------------------------------------------
__global__ __launch_bounds__(256)
void prep(const float* __restrict__ x, ushort_t* __restrict__ xb,
          const float* __restrict__ Wr, const float* __restrict__ Ws,
          ushort_t* __restrict__ Wg,
          const float* __restrict__ W0, const float* __restrict__ W1,
          const float* __restrict__ W2, const float* __restrict__ W3,
          ushort_t* __restrict__ T0, ushort_t* __restrict__ T1,
          ushort_t* __restrict__ T2, ushort_t* __restrict__ T3)
{
    __shared__ float tile[32][33];
    int bid = blockIdx.x;
    int t = threadIdx.x;
    if (bid < 4096) {
        int i = bid * 256 + t;
        float4 v = ((const float4*)x)[i];
        uint2 o;
        o.x = pack2bf(v.x, v.y);
        o.y = pack2bf(v.z, v.w);
        ((uint2*)xb)[i] = o;
    } else if (bid < 4224) {
        int idx = (bid - 4096) * 256 + t;   // 32 x 1024
        int c = idx >> 10, d = idx & 1023;
        float v = 0.f;
        if (c < 15) v = Wr[(size_t)d * 15 + c];
        else if (c < 17) v = Ws[(size_t)d * 2 + (c - 15)];
        Wg[idx] = f2bf(v);
    } else {
        int idx = bid - 4224;               // 4 x 32 x 32 tiles
        int z = idx >> 10, r10 = idx & 1023;
        int k0 = (r10 & 31) * 32, n0 = (r10 >> 5) * 32;
        const float* W; ushort_t* T;
        switch (z) {
            case 0: W = W0; T = T0; break;
            case 1: W = W1; T = T1; break;
            case 2: W = W2; T = T2; break;
            default: W = W3; T = T3; break;
        }
        int r = t >> 3, c4 = (t & 7) * 4;
        float4 v = *(const float4*)&W[(size_t)(k0 + r) * 1024 + n0 + c4];
        tile[r][c4 + 0] = v.x; tile[r][c4 + 1] = v.y;
        tile[r][c4 + 2] = v.z; tile[r][c4 + 3] = v.w;
        __syncthreads();
        int n = t >> 3, kk = (t & 7) * 4;
        uint2 o;
        o.x = pack2bf(tile[kk][n], tile[kk + 1][n]);
        o.y = pack2bf(tile[kk + 2][n], tile[kk + 3][n]);
        *(uint2*)&T[(size_t)(n0 + n) * 1024 + k0 + kk] = o;
    }
}

// ---------------------------------------------------------------------------
// Fused QKV GEMM v8: 256x256 tile, 8 waves (2M x 4N), BK=64, LDS dbuf 128KB,
// 1 block/CU, grid 16x12 (single round, no tail). T3-minimum schedule:
//   STAGE(buf^1, kt+1) -> ds_read frags(buf) -> setprio(1) MFMA setprio(0)
//   -> vmcnt(0) (loads had full compute phase to land) -> barrier. One
// barrier per K-tile. Both-sides XOR swizzle retained (row&7 invariant).
// Per-wave output 128x64 (acc[8][4]); wave's 64-col span = one head, so the
// Q-norm shfl_xor(16/32) reduction ports unchanged. __launch_bounds__(512,2)
// caps regs at 256/wave (8 waves MUST co-reside; R7 lesson: budget acc AGPRs
// in the unified file -> 256 cap is safe for ~215 est, 128 was not).
// ---------------------------------------------------------------------------
__global__ __launch_bounds__(512, 2)
void gemmQKV(const ushort_t* __restrict__ A, const ushort_t* __restrict__ Wt3,
             const float* __restrict__ bq, const float* __restrict__ bk,
             const float* __restrict__ bv,
             ushort_t* __restrict__ Qb, ushort_t* __restrict__ Kw,
             ushort_t* __restrict__ VTw,
             const float* __restrict__ temp, const float* __restrict__ emb)
{
    const int K = 1024;
    const int NT = 16;                     // K / 64
    __shared__ ushort_t As[2][256 * 64];   // 64 KB
    __shared__ ushort_t Bs[2][256 * 64];   // 64 KB

    int t = threadIdx.x;
    int m0 = blockIdx.x * 256;
    int yt = blockIdx.y;                   // n-tile (256 cols)
    int region = yt >> 2;                  // 0=Q 1=K 2=V (4 tiles per region)
    int n0r = (yt & 3) * 256;              // col offset within region
    int n0g = yt * 256;                    // global Wt3 row base

    int lane = t & 63, w = t >> 6;
    int lm = lane & 15, quad = lane >> 4;
    int wr = w >> 2, wc = w & 3;           // 2M x 4N wave grid
    int wm = wr * 128, wn = wc * 64;

    f4 acc[32] = {};   // region2: acc[mi*4+ni]; else (swapped): acc[ni*8+mi]

    // staging map: thread t, round j stages row (t>>3)+64j, chunk t&7;
    // source chunk = (t&7) ^ (row&7); 64j invariant mod 8.
    int srow = t >> 3;                     // 0..63
    int schunk = ((t & 7) ^ (srow & 7)) * 8;
    const ushort_t* pA0 = &A[(size_t)(m0 + srow) * K + schunk];
    const ushort_t* pB0 = &Wt3[(size_t)(n0g + srow) * K + schunk];
    const size_t rstep = (size_t)64 * K;

    // prologue: tile 0 -> buf 0
    {
        #pragma unroll
        for (int j = 0; j < 4; j++) {
            gl2lds16(pA0 + j * rstep, &As[0][(t + j * 512) * 8]);
            gl2lds16(pB0 + j * rstep, &Bs[0][(t + j * 512) * 8]);
        }
    }
    asm volatile("s_waitcnt vmcnt(0)" ::: "memory");
    __builtin_amdgcn_sched_barrier(0);
    __builtin_amdgcn_s_barrier();

    int cur = 0;
    #pragma clang loop unroll(disable)
    for (int kt = 0; kt < NT; ++kt) {
        if (kt + 1 < NT) {                 // issue next-tile stage FIRST
            const ushort_t* sA = pA0 + (kt + 1) * 64;
            const ushort_t* sB = pB0 + (kt + 1) * 64;
            int nb = cur ^ 1;
            #pragma unroll
            for (int j = 0; j < 4; j++) {
                gl2lds16(sA + j * rstep, &As[nb][(t + j * 512) * 8]);
                gl2lds16(sB + j * rstep, &Bs[nb][(t + j * 512) * 8]);
            }
        }
        __builtin_amdgcn_sched_barrier(0);

        #pragma unroll
        for (int ks = 0; ks < 2; ks++) {
            int rc = ((ks * 4 + quad) ^ (lm & 7)) * 8;
            bf8 af[8], bfr[4];
            #pragma unroll
            for (int mi = 0; mi < 8; mi++)
                af[mi] = *(bf8*)&As[cur][(wm + mi * 16 + lm) * 64 + rc];
            #pragma unroll
            for (int ni = 0; ni < 4; ni++)
                bfr[ni] = *(bf8*)&Bs[cur][(wn + ni * 16 + lm) * 64 + rc];
            __builtin_amdgcn_s_setprio(1);
            if (region == 2) {
                #pragma unroll
                for (int mi = 0; mi < 8; mi++)
                #pragma unroll
                for (int ni = 0; ni < 4; ni++)
                    acc[mi * 4 + ni] = __builtin_amdgcn_mfma_f32_16x16x32_bf16(af[mi], bfr[ni], acc[mi * 4 + ni], 0, 0, 0);
            } else {
                #pragma unroll
                for (int ni = 0; ni < 4; ni++)
                #pragma unroll
                for (int mi = 0; mi < 8; mi++)
                    acc[ni * 8 + mi] = __builtin_amdgcn_mfma_f32_16x16x32_bf16(bfr[ni], af[mi], acc[ni * 8 + mi], 0, 0, 0);
            }
            __builtin_amdgcn_s_setprio(0);
        }
        asm volatile("s_waitcnt vmcnt(0)" ::: "memory");
        __builtin_amdgcn_sched_barrier(0);
        __builtin_amdgcn_s_barrier();
        cur ^= 1;
    }

    if (region == 0) {
        int head = (n0r + wn) >> 6;
        float sp = log1pf(__expf(temp[head]));
        float qs = sp * 0.18033688011112042f;   // 0.125 * log2(e)
        f4 bv4[4], ev4[4];
        #pragma unroll
        for (int ni = 0; ni < 4; ni++) {
            bv4[ni] = *(const f4*)&bq[n0r + wn + ni * 16 + quad * 4];
            ev4[ni] = *(const f4*)&emb[head * 64 + ni * 16 + quad * 4];
        }
        #pragma unroll
        for (int mi = 0; mi < 8; mi++) {
            float v[4][4];
            float ss = 0.f;
            #pragma unroll
            for (int ni = 0; ni < 4; ni++)
            #pragma unroll
            for (int i = 0; i < 4; i++) {
                v[ni][i] = acc[ni * 8 + mi][i] + bv4[ni][i];
                ss += v[ni][i] * v[ni][i];
            }
            ss += __shfl_xor(ss, 16, 64);
            ss += __shfl_xor(ss, 32, 64);
            float rs = rsqrtf(ss + 1e-12f);
            int tok = m0 + wm + mi * 16 + lm;
            int b = tok >> 11, s = tok & 2047;
            size_t rowb = (((size_t)(b * 16 + head)) * 2048 + s) * 64;
            #pragma unroll
            for (int ni = 0; ni < 4; ni++) {
                uint2 o;
                o.x = pack2bf((v[ni][0] * rs + ev4[ni][0]) * qs,
                              (v[ni][1] * rs + ev4[ni][1]) * qs);
                o.y = pack2bf((v[ni][2] * rs + ev4[ni][2]) * qs,
                              (v[ni][3] * rs + ev4[ni][3]) * qs);
                *(uint2*)&Qb[rowb + ni * 16 + quad * 4] = o;
            }
        }
    } else if (region == 1) {
        int head = (n0r + wn) >> 6;
        f4 bv4[4];
        #pragma unroll
        for (int ni = 0; ni < 4; ni++)
            bv4[ni] = *(const f4*)&bk[n0r + wn + ni * 16 + quad * 4];
        #pragma unroll
        for (int mi = 0; mi < 8; mi++) {
            int tok = m0 + wm + mi * 16 + lm;
            int b = tok >> 11, s = tok & 2047;
            size_t rowb = (((size_t)(b * 16 + head)) * 2048 + s) * 64;
            #pragma unroll
            for (int ni = 0; ni < 4; ni++) {
                uint2 o;
                o.x = pack2bf(acc[ni * 8 + mi][0] + bv4[ni][0], acc[ni * 8 + mi][1] + bv4[ni][1]);
                o.y = pack2bf(acc[ni * 8 + mi][2] + bv4[ni][2], acc[ni * 8 + mi][3] + bv4[ni][3]);
                *(uint2*)&Kw[rowb + ni * 16 + quad * 4] = o;
            }
        }
    } else {
        float bvv[4];
        #pragma unroll
        for (int ni = 0; ni < 4; ni++) bvv[ni] = bv[n0r + wn + ni * 16 + lm];
        #pragma unroll
        for (int mi = 0; mi < 8; mi++) {
            int gr0 = m0 + wm + mi * 16 + quad * 4;
            int b = gr0 >> 11, s0 = gr0 & 2047;
            #pragma unroll
            for (int ni = 0; ni < 4; ni++) {
                int gc = n0r + wn + ni * 16 + lm;
                int h = gc >> 6, d = gc & 63;
                uint2 o;
                o.x = pack2bf(acc[mi * 4 + ni][0] + bvv[ni], acc[mi * 4 + ni][1] + bvv[ni]);
                o.y = pack2bf(acc[mi * 4 + ni][2] + bvv[ni], acc[mi * 4 + ni][3] + bvv[ni]);
                *(uint2*)&VTw[(((size_t)(b * 16 + h)) * 64 + d) * 2048 + s0] = o;
            }
        }
    }
}

// ---------------------------------------------------------------------------
// Output projection GEMM, swapped operands, fused per-token gate scale.
// EXACT R3 configuration (BK=64 + XOR swizzle). Unchanged this round.
// ---------------------------------------------------------------------------
__global__ __launch_bounds__(256)
void gemmP(const ushort_t* __restrict__ A, const ushort_t* __restrict__ Wt,
           const float* __restrict__ bias, const float* __restrict__ G,
           float* __restrict__ out, int M, int N, int K)
{
    __shared__ ushort_t As[128 * 64];
    __shared__ ushort_t Bs[128 * 64];

    int t = threadIdx.x;
    int m0 = blockIdx.x * 128, n0 = blockIdx.y * 128;
    int lane = t & 63, w = t >> 6;
    int lm = lane & 15, quad = lane >> 4;
    int wm = (w >> 1) * 64, wn = (w & 1) * 64;

    f4 acc[4][4] = {};

    int srow = t >> 3;
    int schunk = ((t & 7) ^ (srow & 7)) * 8;
    const ushort_t* pA = &A[(size_t)(m0 + srow) * K + schunk];
    const ushort_t* pB = &Wt[(size_t)(n0 + srow) * K + schunk];
    const size_t rstep = (size_t)32 * K;

    for (int k0 = 0; k0 < K; k0 += 64) {
        #pragma unroll
        for (int j = 0; j < 4; j++) {
            gl2lds16(pA + j * rstep, &As[(t + j * 256) * 8]);
            gl2lds16(pB + j * rstep, &Bs[(t + j * 256) * 8]);
        }
        pA += 64; pB += 64;
        __syncthreads();

        #pragma unroll
        for (int ks = 0; ks < 2; ks++) {
            int rc = ((ks * 4 + quad) ^ (lm & 7)) * 8;
            bf8 af[4], bfr[4];
            #pragma unroll
            for (int mi = 0; mi < 4; mi++)
                af[mi] = *(bf8*)&As[(wm + mi * 16 + lm) * 64 + rc];
            #pragma unroll
            for (int ni = 0; ni < 4; ni++)
                bfr[ni] = *(bf8*)&Bs[(wn + ni * 16 + lm) * 64 + rc];
            #pragma unroll
            for (int ni = 0; ni < 4; ni++)
            #pragma unroll
            for (int mi = 0; mi < 4; mi++)
                acc[ni][mi] = __builtin_amdgcn_mfma_f32_16x16x32_bf16(bfr[ni], af[mi], acc[ni][mi], 0, 0, 0);
        }
        __syncthreads();
    }

    f4 bv4[4];
    #pragma unroll
    for (int ni = 0; ni < 4; ni++)
        bv4[ni] = *(const f4*)&bias[n0 + wn + ni * 16 + quad * 4];
    #pragma unroll
    for (int mi = 0; mi < 4; mi++) {
        int tok = m0 + wm + mi * 16 + lm;
        float g = G[tok];
        size_t rowb = (size_t)tok * N + n0 + wn;
        #pragma unroll
        for (int ni = 0; ni < 4; ni++) {
            f4 o;
            #pragma unroll
            for (int i = 0; i < 4; i++) o[i] = g * acc[ni][mi][i] + bv4[ni][i];
            *(f4*)&out[rowb + ni * 16 + quad * 4] = o;
        }
    }
}

// ---------------------------------------------------------------------------
// Flash MFMA attention: T14 async staging + exp2-domain P + cvt_pk +
// permlane32_swap exchange. (unchanged, proven)
// ---------------------------------------------------------------------------
__global__ __launch_bounds__(256)
void attn(const ushort_t* __restrict__ Q, const ushort_t* __restrict__ K,
          const ushort_t* __restrict__ VT, ushort_t* __restrict__ Opart,
          float* __restrict__ Lw)
{
    __shared__ ushort_t Ks[64 * 72];       // [key][dim]
    __shared__ ushort_t Vt[64 * 72];       // [dim][key]

    int t = threadIdx.x, lane = t & 63, w = t >> 6;
    int l31 = lane & 31;
    uint_t hi = lane >> 5;
    int bid = blockIdx.x;
    int bh = bid & 31, qt = (bid >> 5) & 15, ks = bid >> 9;
    size_t base = (size_t)bh * 2048 * 64;

    int tok = qt * 128 + w * 32 + l31;
    const ushort_t* qp = &Q[base + (size_t)tok * 64 + hi * 8];
    bf8 qa[4];
    #pragma unroll
    for (int c = 0; c < 4; c++) qa[c] = *(const bf8*)(qp + c * 16);

    float l_part = 0.f;
    f16v o_acc[2] = {};

    int sr = t >> 3, sc = (t & 7) * 8;
    const ushort_t* kp = &K[base + (size_t)(ks * 1024 + sr) * 64 + sc];
    const ushort_t* vp = &VT[base + (size_t)sr * 2048 + ks * 1024 + sc];

    // prologue: load tile 0 into regs
    uint4 rk0 = *(const uint4*)(kp);
    uint4 rk1 = *(const uint4*)(kp + 32 * 64);
    uint4 rv0 = *(const uint4*)(vp);
    uint4 rv1 = *(const uint4*)(vp + 32 * 2048);
    kp += 64 * 64; vp += 64;

    for (int it = 0; it < 16; ++it) {
        *(uint4*)&Ks[sr * 72 + sc] = rk0;
        *(uint4*)&Ks[(sr + 32) * 72 + sc] = rk1;
        *(uint4*)&Vt[sr * 72 + sc] = rv0;
        *(uint4*)&Vt[(sr + 32) * 72 + sc] = rv1;
        __syncthreads();

        // prefetch next tile; latency hidden under this tile's compute
        rk0 = *(const uint4*)(kp);
        rk1 = *(const uint4*)(kp + 32 * 64);
        rv0 = *(const uint4*)(vp);
        rv1 = *(const uint4*)(vp + 32 * 2048);
        kp += 64 * 64; vp += 64;

        bf8 pf[4];
        #pragma unroll
        for (int kt2 = 0; kt2 < 2; kt2++) {
            f16v s = {};
            #pragma unroll
            for (int c = 0; c < 4; c++) {
                bf8 kf = *(bf8*)&Ks[(kt2 * 32 + l31) * 72 + c * 16 + hi * 8];
                s = __builtin_amdgcn_mfma_f32_32x32x16_bf16(kf, qa[c], s, 0, 0, 0);
            }
            uint_t px[4], py[4];
            #pragma unroll
            for (int g = 0; g < 4; g++) {
                float p0 = exp2_fast(s[g * 4 + 0]);
                float p1 = exp2_fast(s[g * 4 + 1]);
                float p2 = exp2_fast(s[g * 4 + 2]);
                float p3 = exp2_fast(s[g * 4 + 3]);
                l_part += (p0 + p1) + (p2 + p3);
                px[g] = cvtpk_bf16(p0, p1);
                py[g] = cvtpk_bf16(p2, p3);
            }
            #pragma unroll
            for (int cc = 0; cc < 2; cc++) {
                uint_t ax = px[2 * cc], bx = px[2 * cc + 1];
                uint_t ay = py[2 * cc], by = py[2 * cc + 1];
                pl32swap(ax, bx);    // ax = u.x (keys j0..3), bx = u.z (j4..7)
                pl32swap(ay, by);    // ay = u.y,              by = u.w
                uint4 u;
                u.x = ax; u.y = ay; u.z = bx; u.w = by;
                pf[kt2 * 2 + cc] = *(bf8*)&u;
            }
        }

        #pragma unroll
        for (int c = 0; c < 4; c++) {
            #pragma unroll
            for (int dt = 0; dt < 2; dt++) {
                bf8 vf = *(bf8*)&Vt[(dt * 32 + l31) * 72 + c * 16 + hi * 8];
                o_acc[dt] = __builtin_amdgcn_mfma_f32_32x32x16_bf16(vf, pf[c], o_acc[dt], 0, 0, 0);
            }
        }
        __syncthreads();
    }

    l_part += __shfl_xor(l_part, 32, 64);
    if (hi == 0) Lw[((size_t)ks * 32 + bh) * 2048 + tok] = l_part;

    size_t pbase = (((size_t)(ks * 32 + bh)) * 2048 + tok) * 64;
    #pragma unroll
    for (int dt = 0; dt < 2; dt++)
    #pragma unroll
    for (int g = 0; g < 4; g++) {
        int d0 = dt * 32 + g * 8 + hi * 4;
        uint2 o;
        o.x = pack2bf_fast(o_acc[dt][g * 4 + 0], o_acc[dt][g * 4 + 1]);
        o.y = pack2bf_fast(o_acc[dt][g * 4 + 2], o_acc[dt][g * 4 + 3]);
        *(uint2*)&Opart[pbase + d0] = o;
    }
}

// ---------------------------------------------------------------------------
// Fused combine + router. Grid 256 x 256: block owns 16 tokens.
// Phase 1: combine split-K partials -> LDS (padded) + global Ob.
// Phase 2 (wave 0): router MFMA from LDS (no 8MB Ob re-read), gate scalar G.
// ---------------------------------------------------------------------------
__global__ __launch_bounds__(256)
void fuseCR(const ushort_t* __restrict__ Opart, const float* __restrict__ Lw,
            const ushort_t* __restrict__ Wg, const float* __restrict__ br,
            const float* __restrict__ bs, ushort_t* __restrict__ Ob,
            float* __restrict__ G)
{
    __shared__ ushort_t Obs[16 * 1032];    // 16 tokens x 1024 dims, +8 pad
    __shared__ float rl_s[16][16];         // [head][token]
    __shared__ float Ls[16][21];

    int t = threadIdx.x;
    int tokg0 = blockIdx.x * 16;
    int b = tokg0 >> 11, st0 = tokg0 & 2047;

    // stage per-(head,token) reciprocal denominators (exactly 256 of them)
    {
        int h = t >> 4, tt = t & 15;
        size_t row = (size_t)(b * 16 + h) * 2048 + st0 + tt;
        rl_s[h][tt] = 1.f / (Lw[row] + Lw[65536 + row]);
    }
    __syncthreads();

    // combine: thread t -> token tt = t>>4, dims dc..dc+3 (uint2 per split)
    {
        int tt = t >> 4, dc = (t & 15) * 4;
        #pragma unroll 4
        for (int h = 0; h < 16; h++) {
            size_t rbase = ((size_t)(b * 16 + h) * 2048 + st0 + tt) * 64 + dc;
            uint2 p0 = *(const uint2*)&Opart[rbase];
            uint2 p1 = *(const uint2*)&Opart[4194304 + rbase];
            float rl = rl_s[h][tt];
            float v0 = (bf2f(p0.x & 0xffff) + bf2f(p1.x & 0xffff)) * rl;
            float v1 = (bf2f(p0.x >> 16)   + bf2f(p1.x >> 16))   * rl;
            float v2 = (bf2f(p0.y & 0xffff) + bf2f(p1.y & 0xffff)) * rl;
            float v3 = (bf2f(p0.y >> 16)   + bf2f(p1.y >> 16))   * rl;
            uint2 o;
            o.x = pack2bf(v0, v1);
            o.y = pack2bf(v2, v3);
            *(uint2*)&Obs[tt * 1032 + h * 64 + dc] = o;
            *(uint2*)&Ob[((size_t)(tokg0 + tt)) * 1024 + h * 64 + dc] = o;
        }
    }
    __syncthreads();

    // router (wave 0 only): logits[16 tok][17] from LDS
    if (t < 64) {
        int lm = t & 15, quad = t >> 4;
        const ushort_t* b0p = &Wg[(size_t)lm * 1024 + quad * 8];
        const ushort_t* b1p = &Wg[(size_t)(16 + lm) * 1024 + quad * 8];
        f4 acc0 = {}, acc1 = {};
        for (int k0 = 0; k0 < 1024; k0 += 32) {
            bf8 a  = *(const bf8*)&Obs[lm * 1032 + k0 + quad * 8];
            bf8 b0 = *(const bf8*)(b0p + k0);
            bf8 b1 = *(const bf8*)(b1p + k0);
            acc0 = __builtin_amdgcn_mfma_f32_16x16x32_bf16(a, b0, acc0, 0, 0, 0);
            acc1 = __builtin_amdgcn_mfma_f32_16x16x32_bf16(a, b1, acc1, 0, 0, 0);
        }
        #pragma unroll
        for (int i = 0; i < 4; i++) {
            int tl = quad * 4 + i;
            Ls[tl][lm] = acc0[i];
            if (lm == 0) Ls[tl][16] = acc1[i];
        }
        waitl0();   // intra-wave LDS ordering before cross-lane read

        if (t < 16) {
            float v[15];
            float mx = -1e30f;
            #pragma unroll
            for (int c = 0; c < 15; c++) { v[c] = Ls[t][c] + br[c]; mx = fmaxf(mx, v[c]); }
            float sum = 0.f;
            #pragma unroll
            for (int c = 0; c < 15; c++) { v[c] = __expf(v[c] - mx); sum += v[c]; }
            float inv = 1.f / sum;
            float t3 = 0.f;
            for (int r = 0; r < 3; r++) {
                int bi = 0; float bv = -1e30f;
                #pragma unroll
                for (int c = 0; c < 15; c++) if (v[c] > bv) { bv = v[c]; bi = c; }
                t3 += bv; v[bi] = -1e30f;
            }
            t3 *= inv;
            float a0 = Ls[t][15] + bs[0], a1 = Ls[t][16] + bs[1];
            float m2 = fmaxf(a0, a1);
            float e0 = __expf(a0 - m2), e1 = __expf(a1 - m2);
            G[tokg0 + t] = (2.f * e0 + 6.f * e1 * t3) / (e0 + e1);
        }
    }
}

// ---------------------------------------------------------------------------
extern "C" void kernel_launch(void* const* d_in, const int* in_sizes, int n_in,
                              void* d_out, int out_size, void* d_ws, size_t ws_size,
                              hipStream_t stream)
{
    const float* x     = (const float*)d_in[0];
    const float* Wq    = (const float*)d_in[1];
    const float* bq    = (const float*)d_in[2];
    const float* Wk    = (const float*)d_in[3];
    const float* bk    = (const float*)d_in[4];
    const float* Wv    = (const float*)d_in[5];
    const float* bv    = (const float*)d_in[6];
    const float* Wproj = (const float*)d_in[7];
    const float* bproj = (const float*)d_in[8];
    const float* Wr    = (const float*)d_in[9];
    const float* br    = (const float*)d_in[10];
    const float* Ws    = (const float*)d_in[11];
    const float* bs    = (const float*)d_in[12];
    const float* temp  = (const float*)d_in[13];
    const float* emb   = (const float*)d_in[14];

    const int M = 4096, N = 1024, Kd = 1024;

    char* ws = (char*)d_ws;
    ushort_t* Kw    = (ushort_t*)ws;                    //  8 MB [B,H,S,64]
    ushort_t* VTw   = (ushort_t*)(ws + 8388608);        //  8 MB [B,H,64,S]
    ushort_t* Qb    = (ushort_t*)(ws + 16777216);       //  8 MB Q; Ob after attn
    ushort_t* Wtp   = (ushort_t*)(ws + 25165824);       //  2 MB Wproj^T
    float*    Gw    = (float*)(ws + 27262976);          // 16 KB
    ushort_t* Wg    = (ushort_t*)(ws + 27279360);       // 64 KB
    float*    Lw    = (float*)(ws + 27344896);          // 512 KB [2][32][2048]
    ushort_t* Wt3   = (ushort_t*)(ws + 27869184);       //  6 MB (dead after QKV)
    ushort_t* xb    = (ushort_t*)(ws + 34160640);       //  8 MB (dead after QKV)
    ushort_t* Opart = (ushort_t*)(ws + 27869184);       // 16 MB, overlays Wt3+xb
    ushort_t* Ob    = Qb;                               // fuseCR writes over Q

    prep<<<8320, 256, 0, stream>>>(x, xb, Wr, Ws, Wg, Wq, Wk, Wv, Wproj,
        Wt3, Wt3 + 1048576, Wt3 + 2097152, Wtp);

    gemmQKV<<<dim3(16, 12), 512, 0, stream>>>(xb, Wt3, bq, bk, bv,
        Qb, Kw, VTw, temp, emb);

    attn<<<1024, 256, 0, stream>>>(Qb, Kw, VTw, Opart, Lw);

    fuseCR<<<256, 256, 0, stream>>>(Opart, Lw, Wg, br, bs, Ob, Gw);

    gemmP<<<dim3(32, 8), 256, 0, stream>>>(Ob, Wtp, bproj, Gw, (float*)d_out, M, N, Kd);
}

// Round 10
// 235.213 us; speedup vs baseline: 1.4465x; 1.4465x over previous
//
#include <hip/hip_runtime.h>
#include <hip/hip_bf16.h>

typedef unsigned short ushort_t;
typedef unsigned int uint_t;

typedef __attribute__((ext_vector_type(8))) short bf8;
typedef __attribute__((ext_vector_type(4))) float f4;
typedef __attribute__((ext_vector_type(16))) float f16v;

__device__ __forceinline__ float bf2f(ushort_t u) {
    unsigned int x = ((unsigned int)u) << 16;
    return __uint_as_float(x);
}
__device__ __forceinline__ ushort_t f2bf(float f) {
    unsigned int x = __float_as_uint(f);
    unsigned int r = x + 0x7fffu + ((x >> 16) & 1u);
    return (ushort_t)(r >> 16);
}
__device__ __forceinline__ uint_t pack2bf(float a, float b) {
    return (uint_t)f2bf(a) | ((uint_t)f2bf(b) << 16);
}
// fast pack: round-half-up + v_perm_b32 byte gather (3 VALU vs ~9)
__device__ __forceinline__ uint_t pack2bf_fast(float a, float b) {
    uint_t au = __float_as_uint(a) + 0x8000u;
    uint_t bu = __float_as_uint(b) + 0x8000u;
    return __builtin_amdgcn_perm(bu, au, 0x07060302);  // lo16=a_hi, hi16=b_hi
}
// v_exp_f32 computes 2^x directly (inputs pre-scaled by log2e at QKV time)
__device__ __forceinline__ float exp2_fast(float x) {
    float r; asm("v_exp_f32 %0, %1" : "=v"(r) : "v"(x)); return r;
}
// 2 f32 -> packed bf16 (RTNE), 1 instr vs 3
__device__ __forceinline__ uint_t cvtpk_bf16(float lo, float hi) {
    uint_t r; asm("v_cvt_pk_bf16_f32 %0, %1, %2" : "=v"(r) : "v"(lo), "v"(hi)); return r;
}
// after: a = [a.lo32, b.lo32], b = [a.hi32, b.hi32]
__device__ __forceinline__ void pl32swap(uint_t &a, uint_t &b) {
    asm("v_permlane32_swap_b32 %0, %1" : "+v"(a), "+v"(b));
}

__device__ __forceinline__ void gl2lds16(const ushort_t* g, ushort_t* l) {
    __builtin_amdgcn_global_load_lds(
        (const __attribute__((address_space(1))) void*)g,
        (__attribute__((address_space(3))) void*)l, 16, 0, 0);
}

__device__ __forceinline__ void waitl0() {
    asm volatile("s_waitcnt lgkmcnt(0)" ::: "memory");
    __builtin_amdgcn_sched_barrier(0);
}

// ---------------------------------------------------------------------------
// prep (merged): [0,4096) x fp32->bf16; [4096,4224) Wg pack; [4224,8320)
// weight transpose-convert (4 matrices, 32x32 tiles)
// ---------------------------------------------------------------------------
__global__ __launch_bounds__(256)
void prep(const float* __restrict__ x, ushort_t* __restrict__ xb,
          const float* __restrict__ Wr, const float* __restrict__ Ws,
          ushort_t* __restrict__ Wg,
          const float* __restrict__ W0, const float* __restrict__ W1,
          const float* __restrict__ W2, const float* __restrict__ W3,
          ushort_t* __restrict__ T0, ushort_t* __restrict__ T1,
          ushort_t* __restrict__ T2, ushort_t* __restrict__ T3)
{
    __shared__ float tile[32][33];
    int bid = blockIdx.x;
    int t = threadIdx.x;
    if (bid < 4096) {
        int i = bid * 256 + t;
        float4 v = ((const float4*)x)[i];
        uint2 o;
        o.x = pack2bf(v.x, v.y);
        o.y = pack2bf(v.z, v.w);
        ((uint2*)xb)[i] = o;
    } else if (bid < 4224) {
        int idx = (bid - 4096) * 256 + t;   // 32 x 1024
        int c = idx >> 10, d = idx & 1023;
        float v = 0.f;
        if (c < 15) v = Wr[(size_t)d * 15 + c];
        else if (c < 17) v = Ws[(size_t)d * 2 + (c - 15)];
        Wg[idx] = f2bf(v);
    } else {
        int idx = bid - 4224;               // 4 x 32 x 32 tiles
        int z = idx >> 10, r10 = idx & 1023;
        int k0 = (r10 & 31) * 32, n0 = (r10 >> 5) * 32;
        const float* W; ushort_t* T;
        switch (z) {
            case 0: W = W0; T = T0; break;
            case 1: W = W1; T = T1; break;
            case 2: W = W2; T = T2; break;
            default: W = W3; T = T3; break;
        }
        int r = t >> 3, c4 = (t & 7) * 4;
        float4 v = *(const float4*)&W[(size_t)(k0 + r) * 1024 + n0 + c4];
        tile[r][c4 + 0] = v.x; tile[r][c4 + 1] = v.y;
        tile[r][c4 + 2] = v.z; tile[r][c4 + 3] = v.w;
        __syncthreads();
        int n = t >> 3, kk = (t & 7) * 4;
        uint2 o;
        o.x = pack2bf(tile[kk][n], tile[kk + 1][n]);
        o.y = pack2bf(tile[kk + 2][n], tile[kk + 3][n]);
        *(uint2*)&T[(size_t)(n0 + n) * 1024 + k0 + kk] = o;
    }
}

// ---------------------------------------------------------------------------
// Fused QKV GEMM: [4096x1024] @ Wt3[3072,1024]^T. Grid (32, 24).
// EXACT R8 configuration (best measured: 57us fast container / 66us slow,
// VGPR 128, 0 conflicts). BK=64, single-buffer 2-barrier, both-sides XOR
// swizzle. 256^2/8-wave port abandoned: R7 (cap-128 spill) + R9 (256-reg
// budget spill, 387MB scratch) prove acc[32]+frags exceed plain-HIP regalloc.
// ---------------------------------------------------------------------------
__global__ __launch_bounds__(256)
void gemmQKV(const ushort_t* __restrict__ A, const ushort_t* __restrict__ Wt3,
             const float* __restrict__ bq, const float* __restrict__ bk,
             const float* __restrict__ bv,
             ushort_t* __restrict__ Qb, ushort_t* __restrict__ Kw,
             ushort_t* __restrict__ VTw,
             const float* __restrict__ temp, const float* __restrict__ emb)
{
    const int K = 1024;
    __shared__ ushort_t As[128 * 64];
    __shared__ ushort_t Bs[128 * 64];

    int t = threadIdx.x;
    int m0 = blockIdx.x * 128;
    int y = blockIdx.y;
    int region = y >> 3;
    int n0 = (y & 7) * 128;

    int lane = t & 63, w = t >> 6;
    int lm = lane & 15, quad = lane >> 4;
    int wm = (w >> 1) * 64, wn = (w & 1) * 64;

    f4 acc[4][4] = {};

    // staging: thread t owns LDS slots ci = t + j*256 (j=0..3) per matrix;
    // row = ci>>3 = (t>>3)+32j, chunk c = t&7. Source chunk = c ^ (row&7);
    // (32j & 7)==0 so the XOR term is constant per thread.
    int srow = t >> 3;
    int schunk = ((t & 7) ^ (srow & 7)) * 8;
    const ushort_t* pA = &A[(size_t)(m0 + srow) * K + schunk];
    const ushort_t* pB = &Wt3[(size_t)(y * 128 + srow) * K + schunk];
    const size_t rstep = (size_t)32 * K;

    for (int k0 = 0; k0 < K; k0 += 64) {
        #pragma unroll
        for (int j = 0; j < 4; j++) {
            gl2lds16(pA + j * rstep, &As[(t + j * 256) * 8]);
            gl2lds16(pB + j * rstep, &Bs[(t + j * 256) * 8]);
        }
        pA += 64; pB += 64;
        __syncthreads();

        #pragma unroll
        for (int ks = 0; ks < 2; ks++) {
            int rc = ((ks * 4 + quad) ^ (lm & 7)) * 8;
            bf8 af[4], bfr[4];
            #pragma unroll
            for (int mi = 0; mi < 4; mi++)
                af[mi] = *(bf8*)&As[(wm + mi * 16 + lm) * 64 + rc];
            #pragma unroll
            for (int ni = 0; ni < 4; ni++)
                bfr[ni] = *(bf8*)&Bs[(wn + ni * 16 + lm) * 64 + rc];
            if (region == 2) {
                #pragma unroll
                for (int mi = 0; mi < 4; mi++)
                #pragma unroll
                for (int ni = 0; ni < 4; ni++)
                    acc[mi][ni] = __builtin_amdgcn_mfma_f32_16x16x32_bf16(af[mi], bfr[ni], acc[mi][ni], 0, 0, 0);
            } else {
                #pragma unroll
                for (int ni = 0; ni < 4; ni++)
                #pragma unroll
                for (int mi = 0; mi < 4; mi++)
                    acc[ni][mi] = __builtin_amdgcn_mfma_f32_16x16x32_bf16(bfr[ni], af[mi], acc[ni][mi], 0, 0, 0);
            }
        }
        __syncthreads();
    }

    if (region == 0) {
        int head = (n0 + wn) >> 6;
        float sp = log1pf(__expf(temp[head]));
        float qs = sp * 0.18033688011112042f;   // 0.125 * log2(e)
        f4 bv4[4], ev4[4];
        #pragma unroll
        for (int ni = 0; ni < 4; ni++) {
            bv4[ni] = *(const f4*)&bq[n0 + wn + ni * 16 + quad * 4];
            ev4[ni] = *(const f4*)&emb[head * 64 + ni * 16 + quad * 4];
        }
        #pragma unroll
        for (int mi = 0; mi < 4; mi++) {
            float v[4][4];
            float ss = 0.f;
            #pragma unroll
            for (int ni = 0; ni < 4; ni++)
            #pragma unroll
            for (int i = 0; i < 4; i++) {
                v[ni][i] = acc[ni][mi][i] + bv4[ni][i];
                ss += v[ni][i] * v[ni][i];
            }
            ss += __shfl_xor(ss, 16, 64);
            ss += __shfl_xor(ss, 32, 64);
            float rs = rsqrtf(ss + 1e-12f);
            int tok = m0 + wm + mi * 16 + lm;
            int b = tok >> 11, s = tok & 2047;
            size_t rowb = (((size_t)(b * 16 + head)) * 2048 + s) * 64;
            #pragma unroll
            for (int ni = 0; ni < 4; ni++) {
                uint2 o;
                o.x = pack2bf((v[ni][0] * rs + ev4[ni][0]) * qs,
                              (v[ni][1] * rs + ev4[ni][1]) * qs);
                o.y = pack2bf((v[ni][2] * rs + ev4[ni][2]) * qs,
                              (v[ni][3] * rs + ev4[ni][3]) * qs);
                *(uint2*)&Qb[rowb + ni * 16 + quad * 4] = o;
            }
        }
    } else if (region == 1) {
        int head = (n0 + wn) >> 6;
        f4 bv4[4];
        #pragma unroll
        for (int ni = 0; ni < 4; ni++)
            bv4[ni] = *(const f4*)&bk[n0 + wn + ni * 16 + quad * 4];
        #pragma unroll
        for (int mi = 0; mi < 4; mi++) {
            int tok = m0 + wm + mi * 16 + lm;
            int b = tok >> 11, s = tok & 2047;
            size_t rowb = (((size_t)(b * 16 + head)) * 2048 + s) * 64;
            #pragma unroll
            for (int ni = 0; ni < 4; ni++) {
                uint2 o;
                o.x = pack2bf(acc[ni][mi][0] + bv4[ni][0], acc[ni][mi][1] + bv4[ni][1]);
                o.y = pack2bf(acc[ni][mi][2] + bv4[ni][2], acc[ni][mi][3] + bv4[ni][3]);
                *(uint2*)&Kw[rowb + ni * 16 + quad * 4] = o;
            }
        }
    } else {
        float bvv[4];
        #pragma unroll
        for (int ni = 0; ni < 4; ni++) bvv[ni] = bv[n0 + wn + ni * 16 + lm];
        #pragma unroll
        for (int mi = 0; mi < 4; mi++) {
            int gr0 = m0 + wm + mi * 16 + quad * 4;
            int b = gr0 >> 11, s0 = gr0 & 2047;
            #pragma unroll
            for (int ni = 0; ni < 4; ni++) {
                int gc = n0 + wn + ni * 16 + lm;
                int h = gc >> 6, d = gc & 63;
                uint2 o;
                o.x = pack2bf(acc[mi][ni][0] + bvv[ni], acc[mi][ni][1] + bvv[ni]);
                o.y = pack2bf(acc[mi][ni][2] + bvv[ni], acc[mi][ni][3] + bvv[ni]);
                *(uint2*)&VTw[(((size_t)(b * 16 + h)) * 64 + d) * 2048 + s0] = o;
            }
        }
    }
}

// ---------------------------------------------------------------------------
// Output projection GEMM v9: 64x128 tile -> grid (64,8) = 512 blocks =
// 2 blocks/CU (was 256 = 1/CU, grid-capped TLP). Mechanism: every session
// regression (R5/R6) showed these latency-bound loops scale ~linearly with
// resident waves; gemmP was the only GEMM whose occupancy was grid-limited.
// Same BK=64 + both-sides XOR swizzle inner loop. acc[4][2]=32 AGPR,
// LDS 24KB. Waves 2x2, per-wave output 32x64.
// ---------------------------------------------------------------------------
__global__ __launch_bounds__(256)
void gemmP(const ushort_t* __restrict__ A, const ushort_t* __restrict__ Wt,
           const float* __restrict__ bias, const float* __restrict__ G,
           float* __restrict__ out, int M, int N, int K)
{
    __shared__ ushort_t As[64 * 64];     //  8 KB
    __shared__ ushort_t Bs[128 * 64];    // 16 KB

    int t = threadIdx.x;
    int m0 = blockIdx.x * 64, n0 = blockIdx.y * 128;
    int lane = t & 63, w = t >> 6;
    int lm = lane & 15, quad = lane >> 4;
    int wm = (w >> 1) * 32, wn = (w & 1) * 64;

    f4 acc[4][2] = {};

    int srow = t >> 3;
    int schunk = ((t & 7) ^ (srow & 7)) * 8;
    const ushort_t* pA = &A[(size_t)(m0 + srow) * K + schunk];
    const ushort_t* pB = &Wt[(size_t)(n0 + srow) * K + schunk];
    const size_t rstep = (size_t)32 * K;

    for (int k0 = 0; k0 < K; k0 += 64) {
        // A: rows (t>>3)+32j, j=0..1; B: j=0..3. 32j%8==0 -> swizzle const.
        gl2lds16(pA, &As[t * 8]);
        gl2lds16(pA + rstep, &As[(t + 256) * 8]);
        #pragma unroll
        for (int j = 0; j < 4; j++)
            gl2lds16(pB + j * rstep, &Bs[(t + j * 256) * 8]);
        pA += 64; pB += 64;
        __syncthreads();

        #pragma unroll
        for (int ks = 0; ks < 2; ks++) {
            int rc = ((ks * 4 + quad) ^ (lm & 7)) * 8;
            bf8 af[2], bfr[4];
            #pragma unroll
            for (int mi = 0; mi < 2; mi++)
                af[mi] = *(bf8*)&As[(wm + mi * 16 + lm) * 64 + rc];
            #pragma unroll
            for (int ni = 0; ni < 4; ni++)
                bfr[ni] = *(bf8*)&Bs[(wn + ni * 16 + lm) * 64 + rc];
            #pragma unroll
            for (int ni = 0; ni < 4; ni++)
            #pragma unroll
            for (int mi = 0; mi < 2; mi++)
                acc[ni][mi] = __builtin_amdgcn_mfma_f32_16x16x32_bf16(bfr[ni], af[mi], acc[ni][mi], 0, 0, 0);
        }
        __syncthreads();
    }

    f4 bv4[4];
    #pragma unroll
    for (int ni = 0; ni < 4; ni++)
        bv4[ni] = *(const f4*)&bias[n0 + wn + ni * 16 + quad * 4];
    #pragma unroll
    for (int mi = 0; mi < 2; mi++) {
        int tok = m0 + wm + mi * 16 + lm;
        float g = G[tok];
        size_t rowb = (size_t)tok * N + n0 + wn;
        #pragma unroll
        for (int ni = 0; ni < 4; ni++) {
            f4 o;
            #pragma unroll
            for (int i = 0; i < 4; i++) o[i] = g * acc[ni][mi][i] + bv4[ni][i];
            *(f4*)&out[rowb + ni * 16 + quad * 4] = o;
        }
    }
}

// ---------------------------------------------------------------------------
// Flash MFMA attention: T14 async staging + exp2-domain P + cvt_pk +
// permlane32_swap exchange. (unchanged, proven)
// ---------------------------------------------------------------------------
__global__ __launch_bounds__(256)
void attn(const ushort_t* __restrict__ Q, const ushort_t* __restrict__ K,
          const ushort_t* __restrict__ VT, ushort_t* __restrict__ Opart,
          float* __restrict__ Lw)
{
    __shared__ ushort_t Ks[64 * 72];       // [key][dim]
    __shared__ ushort_t Vt[64 * 72];       // [dim][key]

    int t = threadIdx.x, lane = t & 63, w = t >> 6;
    int l31 = lane & 31;
    uint_t hi = lane >> 5;
    int bid = blockIdx.x;
    int bh = bid & 31, qt = (bid >> 5) & 15, ks = bid >> 9;
    size_t base = (size_t)bh * 2048 * 64;

    int tok = qt * 128 + w * 32 + l31;
    const ushort_t* qp = &Q[base + (size_t)tok * 64 + hi * 8];
    bf8 qa[4];
    #pragma unroll
    for (int c = 0; c < 4; c++) qa[c] = *(const bf8*)(qp + c * 16);

    float l_part = 0.f;
    f16v o_acc[2] = {};

    int sr = t >> 3, sc = (t & 7) * 8;
    const ushort_t* kp = &K[base + (size_t)(ks * 1024 + sr) * 64 + sc];
    const ushort_t* vp = &VT[base + (size_t)sr * 2048 + ks * 1024 + sc];

    // prologue: load tile 0 into regs
    uint4 rk0 = *(const uint4*)(kp);
    uint4 rk1 = *(const uint4*)(kp + 32 * 64);
    uint4 rv0 = *(const uint4*)(vp);
    uint4 rv1 = *(const uint4*)(vp + 32 * 2048);
    kp += 64 * 64; vp += 64;

    for (int it = 0; it < 16; ++it) {
        *(uint4*)&Ks[sr * 72 + sc] = rk0;
        *(uint4*)&Ks[(sr + 32) * 72 + sc] = rk1;
        *(uint4*)&Vt[sr * 72 + sc] = rv0;
        *(uint4*)&Vt[(sr + 32) * 72 + sc] = rv1;
        __syncthreads();

        // prefetch next tile; latency hidden under this tile's compute
        rk0 = *(const uint4*)(kp);
        rk1 = *(const uint4*)(kp + 32 * 64);
        rv0 = *(const uint4*)(vp);
        rv1 = *(const uint4*)(vp + 32 * 2048);
        kp += 64 * 64; vp += 64;

        bf8 pf[4];
        #pragma unroll
        for (int kt2 = 0; kt2 < 2; kt2++) {
            f16v s = {};
            #pragma unroll
            for (int c = 0; c < 4; c++) {
                bf8 kf = *(bf8*)&Ks[(kt2 * 32 + l31) * 72 + c * 16 + hi * 8];
                s = __builtin_amdgcn_mfma_f32_32x32x16_bf16(kf, qa[c], s, 0, 0, 0);
            }
            uint_t px[4], py[4];
            #pragma unroll
            for (int g = 0; g < 4; g++) {
                float p0 = exp2_fast(s[g * 4 + 0]);
                float p1 = exp2_fast(s[g * 4 + 1]);
                float p2 = exp2_fast(s[g * 4 + 2]);
                float p3 = exp2_fast(s[g * 4 + 3]);
                l_part += (p0 + p1) + (p2 + p3);
                px[g] = cvtpk_bf16(p0, p1);
                py[g] = cvtpk_bf16(p2, p3);
            }
            #pragma unroll
            for (int cc = 0; cc < 2; cc++) {
                uint_t ax = px[2 * cc], bx = px[2 * cc + 1];
                uint_t ay = py[2 * cc], by = py[2 * cc + 1];
                pl32swap(ax, bx);    // ax = u.x (keys j0..3), bx = u.z (j4..7)
                pl32swap(ay, by);    // ay = u.y,              by = u.w
                uint4 u;
                u.x = ax; u.y = ay; u.z = bx; u.w = by;
                pf[kt2 * 2 + cc] = *(bf8*)&u;
            }
        }

        #pragma unroll
        for (int c = 0; c < 4; c++) {
            #pragma unroll
            for (int dt = 0; dt < 2; dt++) {
                bf8 vf = *(bf8*)&Vt[(dt * 32 + l31) * 72 + c * 16 + hi * 8];
                o_acc[dt] = __builtin_amdgcn_mfma_f32_32x32x16_bf16(vf, pf[c], o_acc[dt], 0, 0, 0);
            }
        }
        __syncthreads();
    }

    l_part += __shfl_xor(l_part, 32, 64);
    if (hi == 0) Lw[((size_t)ks * 32 + bh) * 2048 + tok] = l_part;

    size_t pbase = (((size_t)(ks * 32 + bh)) * 2048 + tok) * 64;
    #pragma unroll
    for (int dt = 0; dt < 2; dt++)
    #pragma unroll
    for (int g = 0; g < 4; g++) {
        int d0 = dt * 32 + g * 8 + hi * 4;
        uint2 o;
        o.x = pack2bf_fast(o_acc[dt][g * 4 + 0], o_acc[dt][g * 4 + 1]);
        o.y = pack2bf_fast(o_acc[dt][g * 4 + 2], o_acc[dt][g * 4 + 3]);
        *(uint2*)&Opart[pbase + d0] = o;
    }
}

// ---------------------------------------------------------------------------
// Fused combine + router. Grid 256 x 256: block owns 16 tokens.
// Phase 1: combine split-K partials -> LDS (padded) + global Ob.
// Phase 2 (wave 0): router MFMA from LDS (no 8MB Ob re-read), gate scalar G.
// ---------------------------------------------------------------------------
__global__ __launch_bounds__(256)
void fuseCR(const ushort_t* __restrict__ Opart, const float* __restrict__ Lw,
            const ushort_t* __restrict__ Wg, const float* __restrict__ br,
            const float* __restrict__ bs, ushort_t* __restrict__ Ob,
            float* __restrict__ G)
{
    __shared__ ushort_t Obs[16 * 1032];    // 16 tokens x 1024 dims, +8 pad
    __shared__ float rl_s[16][16];         // [head][token]
    __shared__ float Ls[16][21];

    int t = threadIdx.x;
    int tokg0 = blockIdx.x * 16;
    int b = tokg0 >> 11, st0 = tokg0 & 2047;

    // stage per-(head,token) reciprocal denominators (exactly 256 of them)
    {
        int h = t >> 4, tt = t & 15;
        size_t row = (size_t)(b * 16 + h) * 2048 + st0 + tt;
        rl_s[h][tt] = 1.f / (Lw[row] + Lw[65536 + row]);
    }
    __syncthreads();

    // combine: thread t -> token tt = t>>4, dims dc..dc+3 (uint2 per split)
    {
        int tt = t >> 4, dc = (t & 15) * 4;
        #pragma unroll 4
        for (int h = 0; h < 16; h++) {
            size_t rbase = ((size_t)(b * 16 + h) * 2048 + st0 + tt) * 64 + dc;
            uint2 p0 = *(const uint2*)&Opart[rbase];
            uint2 p1 = *(const uint2*)&Opart[4194304 + rbase];
            float rl = rl_s[h][tt];
            float v0 = (bf2f(p0.x & 0xffff) + bf2f(p1.x & 0xffff)) * rl;
            float v1 = (bf2f(p0.x >> 16)   + bf2f(p1.x >> 16))   * rl;
            float v2 = (bf2f(p0.y & 0xffff) + bf2f(p1.y & 0xffff)) * rl;
            float v3 = (bf2f(p0.y >> 16)   + bf2f(p1.y >> 16))   * rl;
            uint2 o;
            o.x = pack2bf(v0, v1);
            o.y = pack2bf(v2, v3);
            *(uint2*)&Obs[tt * 1032 + h * 64 + dc] = o;
            *(uint2*)&Ob[((size_t)(tokg0 + tt)) * 1024 + h * 64 + dc] = o;
        }
    }
    __syncthreads();

    // router (wave 0 only): logits[16 tok][17] from LDS
    if (t < 64) {
        int lm = t & 15, quad = t >> 4;
        const ushort_t* b0p = &Wg[(size_t)lm * 1024 + quad * 8];
        const ushort_t* b1p = &Wg[(size_t)(16 + lm) * 1024 + quad * 8];
        f4 acc0 = {}, acc1 = {};
        for (int k0 = 0; k0 < 1024; k0 += 32) {
            bf8 a  = *(const bf8*)&Obs[lm * 1032 + k0 + quad * 8];
            bf8 b0 = *(const bf8*)(b0p + k0);
            bf8 b1 = *(const bf8*)(b1p + k0);
            acc0 = __builtin_amdgcn_mfma_f32_16x16x32_bf16(a, b0, acc0, 0, 0, 0);
            acc1 = __builtin_amdgcn_mfma_f32_16x16x32_bf16(a, b1, acc1, 0, 0, 0);
        }
        #pragma unroll
        for (int i = 0; i < 4; i++) {
            int tl = quad * 4 + i;
            Ls[tl][lm] = acc0[i];
            if (lm == 0) Ls[tl][16] = acc1[i];
        }
        waitl0();   // intra-wave LDS ordering before cross-lane read

        if (t < 16) {
            float v[15];
            float mx = -1e30f;
            #pragma unroll
            for (int c = 0; c < 15; c++) { v[c] = Ls[t][c] + br[c]; mx = fmaxf(mx, v[c]); }
            float sum = 0.f;
            #pragma unroll
            for (int c = 0; c < 15; c++) { v[c] = __expf(v[c] - mx); sum += v[c]; }
            float inv = 1.f / sum;
            float t3 = 0.f;
            for (int r = 0; r < 3; r++) {
                int bi = 0; float bv = -1e30f;
                #pragma unroll
                for (int c = 0; c < 15; c++) if (v[c] > bv) { bv = v[c]; bi = c; }
                t3 += bv; v[bi] = -1e30f;
            }
            t3 *= inv;
            float a0 = Ls[t][15] + bs[0], a1 = Ls[t][16] + bs[1];
            float m2 = fmaxf(a0, a1);
            float e0 = __expf(a0 - m2), e1 = __expf(a1 - m2);
            G[tokg0 + t] = (2.f * e0 + 6.f * e1 * t3) / (e0 + e1);
        }
    }
}

// ---------------------------------------------------------------------------
extern "C" void kernel_launch(void* const* d_in, const int* in_sizes, int n_in,
                              void* d_out, int out_size, void* d_ws, size_t ws_size,
                              hipStream_t stream)
{
    const float* x     = (const float*)d_in[0];
    const float* Wq    = (const float*)d_in[1];
    const float* bq    = (const float*)d_in[2];
    const float* Wk    = (const float*)d_in[3];
    const float* bk    = (const float*)d_in[4];
    const float* Wv    = (const float*)d_in[5];
    const float* bv    = (const float*)d_in[6];
    const float* Wproj = (const float*)d_in[7];
    const float* bproj = (const float*)d_in[8];
    const float* Wr    = (const float*)d_in[9];
    const float* br    = (const float*)d_in[10];
    const float* Ws    = (const float*)d_in[11];
    const float* bs    = (const float*)d_in[12];
    const float* temp  = (const float*)d_in[13];
    const float* emb   = (const float*)d_in[14];

    const int M = 4096, N = 1024, Kd = 1024;

    char* ws = (char*)d_ws;
    ushort_t* Kw    = (ushort_t*)ws;                    //  8 MB [B,H,S,64]
    ushort_t* VTw   = (ushort_t*)(ws + 8388608);        //  8 MB [B,H,64,S]
    ushort_t* Qb    = (ushort_t*)(ws + 16777216);       //  8 MB Q; Ob after attn
    ushort_t* Wtp   = (ushort_t*)(ws + 25165824);       //  2 MB Wproj^T
    float*    Gw    = (float*)(ws + 27262976);          // 16 KB
    ushort_t* Wg    = (ushort_t*)(ws + 27279360);       // 64 KB
    float*    Lw    = (float*)(ws + 27344896);          // 512 KB [2][32][2048]
    ushort_t* Wt3   = (ushort_t*)(ws + 27869184);       //  6 MB (dead after QKV)
    ushort_t* xb    = (ushort_t*)(ws + 34160640);       //  8 MB (dead after QKV)
    ushort_t* Opart = (ushort_t*)(ws + 27869184);       // 16 MB, overlays Wt3+xb
    ushort_t* Ob    = Qb;                               // fuseCR writes over Q

    prep<<<8320, 256, 0, stream>>>(x, xb, Wr, Ws, Wg, Wq, Wk, Wv, Wproj,
        Wt3, Wt3 + 1048576, Wt3 + 2097152, Wtp);

    gemmQKV<<<dim3(32, 24), 256, 0, stream>>>(xb, Wt3, bq, bk, bv,
        Qb, Kw, VTw, temp, emb);

    attn<<<1024, 256, 0, stream>>>(Qb, Kw, VTw, Opart, Lw);

    fuseCR<<<256, 256, 0, stream>>>(Opart, Lw, Wg, br, bs, Ob, Gw);

    gemmP<<<dim3(64, 8), 256, 0, stream>>>(Ob, Wtp, bproj, Gw, (float*)d_out, M, N, Kd);
}

// Round 11
// 231.295 us; speedup vs baseline: 1.4710x; 1.0169x over previous
//
#include <hip/hip_runtime.h>
#include <hip/hip_bf16.h>

typedef unsigned short ushort_t;
typedef unsigned int uint_t;

typedef __attribute__((ext_vector_type(8))) short bf8;
typedef __attribute__((ext_vector_type(4))) float f4;
typedef __attribute__((ext_vector_type(16))) float f16v;

__device__ __forceinline__ float bf2f(ushort_t u) {
    unsigned int x = ((unsigned int)u) << 16;
    return __uint_as_float(x);
}
__device__ __forceinline__ ushort_t f2bf(float f) {
    unsigned int x = __float_as_uint(f);
    unsigned int r = x + 0x7fffu + ((x >> 16) & 1u);
    return (ushort_t)(r >> 16);
}
__device__ __forceinline__ uint_t pack2bf(float a, float b) {
    return (uint_t)f2bf(a) | ((uint_t)f2bf(b) << 16);
}
// fast pack: round-half-up + v_perm_b32 byte gather (3 VALU vs ~9)
__device__ __forceinline__ uint_t pack2bf_fast(float a, float b) {
    uint_t au = __float_as_uint(a) + 0x8000u;
    uint_t bu = __float_as_uint(b) + 0x8000u;
    return __builtin_amdgcn_perm(bu, au, 0x07060302);  // lo16=a_hi, hi16=b_hi
}
// v_exp_f32 computes 2^x directly (inputs pre-scaled by log2e at QKV time)
__device__ __forceinline__ float exp2_fast(float x) {
    float r; asm("v_exp_f32 %0, %1" : "=v"(r) : "v"(x)); return r;
}
// 2 f32 -> packed bf16 (RTNE), 1 instr vs 3
__device__ __forceinline__ uint_t cvtpk_bf16(float lo, float hi) {
    uint_t r; asm("v_cvt_pk_bf16_f32 %0, %1, %2" : "=v"(r) : "v"(lo), "v"(hi)); return r;
}
// after: a = [a.lo32, b.lo32], b = [a.hi32, b.hi32]
__device__ __forceinline__ void pl32swap(uint_t &a, uint_t &b) {
    asm("v_permlane32_swap_b32 %0, %1" : "+v"(a), "+v"(b));
}

__device__ __forceinline__ void gl2lds16(const ushort_t* g, ushort_t* l) {
    __builtin_amdgcn_global_load_lds(
        (const __attribute__((address_space(1))) void*)g,
        (__attribute__((address_space(3))) void*)l, 16, 0, 0);
}

__device__ __forceinline__ void waitl0() {
    asm volatile("s_waitcnt lgkmcnt(0)" ::: "memory");
    __builtin_amdgcn_sched_barrier(0);
}

// ---------------------------------------------------------------------------
// prep (merged): [0,4096) x fp32->bf16; [4096,4224) Wg pack; [4224,8320)
// weight transpose-convert (4 matrices, 32x32 tiles)
// ---------------------------------------------------------------------------
__global__ __launch_bounds__(256)
void prep(const float* __restrict__ x, ushort_t* __restrict__ xb,
          const float* __restrict__ Wr, const float* __restrict__ Ws,
          ushort_t* __restrict__ Wg,
          const float* __restrict__ W0, const float* __restrict__ W1,
          const float* __restrict__ W2, const float* __restrict__ W3,
          ushort_t* __restrict__ T0, ushort_t* __restrict__ T1,
          ushort_t* __restrict__ T2, ushort_t* __restrict__ T3)
{
    __shared__ float tile[32][33];
    int bid = blockIdx.x;
    int t = threadIdx.x;
    if (bid < 4096) {
        int i = bid * 256 + t;
        float4 v = ((const float4*)x)[i];
        uint2 o;
        o.x = pack2bf(v.x, v.y);
        o.y = pack2bf(v.z, v.w);
        ((uint2*)xb)[i] = o;
    } else if (bid < 4224) {
        int idx = (bid - 4096) * 256 + t;   // 32 x 1024
        int c = idx >> 10, d = idx & 1023;
        float v = 0.f;
        if (c < 15) v = Wr[(size_t)d * 15 + c];
        else if (c < 17) v = Ws[(size_t)d * 2 + (c - 15)];
        Wg[idx] = f2bf(v);
    } else {
        int idx = bid - 4224;               // 4 x 32 x 32 tiles
        int z = idx >> 10, r10 = idx & 1023;
        int k0 = (r10 & 31) * 32, n0 = (r10 >> 5) * 32;
        const float* W; ushort_t* T;
        switch (z) {
            case 0: W = W0; T = T0; break;
            case 1: W = W1; T = T1; break;
            case 2: W = W2; T = T2; break;
            default: W = W3; T = T3; break;
        }
        int r = t >> 3, c4 = (t & 7) * 4;
        float4 v = *(const float4*)&W[(size_t)(k0 + r) * 1024 + n0 + c4];
        tile[r][c4 + 0] = v.x; tile[r][c4 + 1] = v.y;
        tile[r][c4 + 2] = v.z; tile[r][c4 + 3] = v.w;
        __syncthreads();
        int n = t >> 3, kk = (t & 7) * 4;
        uint2 o;
        o.x = pack2bf(tile[kk][n], tile[kk + 1][n]);
        o.y = pack2bf(tile[kk + 2][n], tile[kk + 3][n]);
        *(uint2*)&T[(size_t)(n0 + n) * 1024 + k0 + kk] = o;
    }
}

// ---------------------------------------------------------------------------
// Fused QKV GEMM v10: 128x64 tile -> grid (32,48) = 1536 blocks. R10's gemmP
// lesson applied: gemmQKV was GRID-limited at 3 blocks/CU (768/256); smaller
// tile doubles the grid -> 4 blocks/CU (VGPR-limited), 16 resident waves.
// acc halves to 8xf4 = 32 AGPR (VGPR ~110, safely under the 128 cliff).
// LDS 24KB. Waves 4Mx1N: each wave spans exactly one 64-col head -> Q-norm
// shfl reduction and all epilogues port with loop bounds only (mi<2).
// Inner loop = proven R8 structure: BK=64, 2-barrier, both-sides XOR swizzle.
// ---------------------------------------------------------------------------
__global__ __launch_bounds__(256)
void gemmQKV(const ushort_t* __restrict__ A, const ushort_t* __restrict__ Wt3,
             const float* __restrict__ bq, const float* __restrict__ bk,
             const float* __restrict__ bv,
             ushort_t* __restrict__ Qb, ushort_t* __restrict__ Kw,
             ushort_t* __restrict__ VTw,
             const float* __restrict__ temp, const float* __restrict__ emb)
{
    const int K = 1024;
    __shared__ ushort_t As[128 * 64];   // 16 KB
    __shared__ ushort_t Bs[64 * 64];    //  8 KB

    int t = threadIdx.x;
    int m0 = blockIdx.x * 128;
    int y = blockIdx.y;                 // 48 tiles of 64 cols
    int region = y >> 4;                // 0=Q 1=K 2=V
    int n0r = (y & 15) * 64;            // col offset within region
    int head = y & 15;

    int lane = t & 63, w = t >> 6;
    int lm = lane & 15, quad = lane >> 4;
    int wm = w * 32;                    // 4 waves stacked in M

    f4 acc[8] = {};   // region2: acc[mi*4+ni]; else (swapped): acc[ni*2+mi]

    // staging: A rows (t>>3)+32j (j=0..3), B rows (t>>3)+32j (j=0..1);
    // chunk c = t&7, source chunk = c ^ (row&7); 32j%8==0 -> const/thread.
    int srow = t >> 3;
    int schunk = ((t & 7) ^ (srow & 7)) * 8;
    const ushort_t* pA = &A[(size_t)(m0 + srow) * K + schunk];
    const ushort_t* pB = &Wt3[(size_t)(y * 64 + srow) * K + schunk];
    const size_t rstep = (size_t)32 * K;

    for (int k0 = 0; k0 < K; k0 += 64) {
        #pragma unroll
        for (int j = 0; j < 4; j++)
            gl2lds16(pA + j * rstep, &As[(t + j * 256) * 8]);
        #pragma unroll
        for (int j = 0; j < 2; j++)
            gl2lds16(pB + j * rstep, &Bs[(t + j * 256) * 8]);
        pA += 64; pB += 64;
        __syncthreads();

        #pragma unroll
        for (int ks = 0; ks < 2; ks++) {
            int rc = ((ks * 4 + quad) ^ (lm & 7)) * 8;
            bf8 af[2], bfr[4];
            #pragma unroll
            for (int mi = 0; mi < 2; mi++)
                af[mi] = *(bf8*)&As[(wm + mi * 16 + lm) * 64 + rc];
            #pragma unroll
            for (int ni = 0; ni < 4; ni++)
                bfr[ni] = *(bf8*)&Bs[(ni * 16 + lm) * 64 + rc];
            if (region == 2) {
                #pragma unroll
                for (int mi = 0; mi < 2; mi++)
                #pragma unroll
                for (int ni = 0; ni < 4; ni++)
                    acc[mi * 4 + ni] = __builtin_amdgcn_mfma_f32_16x16x32_bf16(af[mi], bfr[ni], acc[mi * 4 + ni], 0, 0, 0);
            } else {
                #pragma unroll
                for (int ni = 0; ni < 4; ni++)
                #pragma unroll
                for (int mi = 0; mi < 2; mi++)
                    acc[ni * 2 + mi] = __builtin_amdgcn_mfma_f32_16x16x32_bf16(bfr[ni], af[mi], acc[ni * 2 + mi], 0, 0, 0);
            }
        }
        __syncthreads();
    }

    if (region == 0) {
        float sp = log1pf(__expf(temp[head]));
        float qs = sp * 0.18033688011112042f;   // 0.125 * log2(e)
        f4 bv4[4], ev4[4];
        #pragma unroll
        for (int ni = 0; ni < 4; ni++) {
            bv4[ni] = *(const f4*)&bq[n0r + ni * 16 + quad * 4];
            ev4[ni] = *(const f4*)&emb[head * 64 + ni * 16 + quad * 4];
        }
        #pragma unroll
        for (int mi = 0; mi < 2; mi++) {
            float v[4][4];
            float ss = 0.f;
            #pragma unroll
            for (int ni = 0; ni < 4; ni++)
            #pragma unroll
            for (int i = 0; i < 4; i++) {
                v[ni][i] = acc[ni * 2 + mi][i] + bv4[ni][i];
                ss += v[ni][i] * v[ni][i];
            }
            ss += __shfl_xor(ss, 16, 64);
            ss += __shfl_xor(ss, 32, 64);
            float rs = rsqrtf(ss + 1e-12f);
            int tok = m0 + wm + mi * 16 + lm;
            int b = tok >> 11, s = tok & 2047;
            size_t rowb = (((size_t)(b * 16 + head)) * 2048 + s) * 64;
            #pragma unroll
            for (int ni = 0; ni < 4; ni++) {
                uint2 o;
                o.x = pack2bf((v[ni][0] * rs + ev4[ni][0]) * qs,
                              (v[ni][1] * rs + ev4[ni][1]) * qs);
                o.y = pack2bf((v[ni][2] * rs + ev4[ni][2]) * qs,
                              (v[ni][3] * rs + ev4[ni][3]) * qs);
                *(uint2*)&Qb[rowb + ni * 16 + quad * 4] = o;
            }
        }
    } else if (region == 1) {
        f4 bv4[4];
        #pragma unroll
        for (int ni = 0; ni < 4; ni++)
            bv4[ni] = *(const f4*)&bk[n0r + ni * 16 + quad * 4];
        #pragma unroll
        for (int mi = 0; mi < 2; mi++) {
            int tok = m0 + wm + mi * 16 + lm;
            int b = tok >> 11, s = tok & 2047;
            size_t rowb = (((size_t)(b * 16 + head)) * 2048 + s) * 64;
            #pragma unroll
            for (int ni = 0; ni < 4; ni++) {
                uint2 o;
                o.x = pack2bf(acc[ni * 2 + mi][0] + bv4[ni][0], acc[ni * 2 + mi][1] + bv4[ni][1]);
                o.y = pack2bf(acc[ni * 2 + mi][2] + bv4[ni][2], acc[ni * 2 + mi][3] + bv4[ni][3]);
                *(uint2*)&Kw[rowb + ni * 16 + quad * 4] = o;
            }
        }
    } else {
        float bvv[4];
        #pragma unroll
        for (int ni = 0; ni < 4; ni++) bvv[ni] = bv[n0r + ni * 16 + lm];
        #pragma unroll
        for (int mi = 0; mi < 2; mi++) {
            int gr0 = m0 + wm + mi * 16 + quad * 4;
            int b = gr0 >> 11, s0 = gr0 & 2047;
            #pragma unroll
            for (int ni = 0; ni < 4; ni++) {
                int d = ni * 16 + lm;
                uint2 o;
                o.x = pack2bf(acc[mi * 4 + ni][0] + bvv[ni], acc[mi * 4 + ni][1] + bvv[ni]);
                o.y = pack2bf(acc[mi * 4 + ni][2] + bvv[ni], acc[mi * 4 + ni][3] + bvv[ni]);
                *(uint2*)&VTw[(((size_t)(b * 16 + head)) * 64 + d) * 2048 + s0] = o;
            }
        }
    }
}

// ---------------------------------------------------------------------------
// Output projection GEMM v9 (proven R10): 64x128 tile, grid (64,8) = 512
// blocks = 2 blocks/CU. BK=64 + both-sides XOR swizzle. Unchanged.
// ---------------------------------------------------------------------------
__global__ __launch_bounds__(256)
void gemmP(const ushort_t* __restrict__ A, const ushort_t* __restrict__ Wt,
           const float* __restrict__ bias, const float* __restrict__ G,
           float* __restrict__ out, int M, int N, int K)
{
    __shared__ ushort_t As[64 * 64];     //  8 KB
    __shared__ ushort_t Bs[128 * 64];    // 16 KB

    int t = threadIdx.x;
    int m0 = blockIdx.x * 64, n0 = blockIdx.y * 128;
    int lane = t & 63, w = t >> 6;
    int lm = lane & 15, quad = lane >> 4;
    int wm = (w >> 1) * 32, wn = (w & 1) * 64;

    f4 acc[4][2] = {};

    int srow = t >> 3;
    int schunk = ((t & 7) ^ (srow & 7)) * 8;
    const ushort_t* pA = &A[(size_t)(m0 + srow) * K + schunk];
    const ushort_t* pB = &Wt[(size_t)(n0 + srow) * K + schunk];
    const size_t rstep = (size_t)32 * K;

    for (int k0 = 0; k0 < K; k0 += 64) {
        // A: rows (t>>3)+32j, j=0..1; B: j=0..3. 32j%8==0 -> swizzle const.
        gl2lds16(pA, &As[t * 8]);
        gl2lds16(pA + rstep, &As[(t + 256) * 8]);
        #pragma unroll
        for (int j = 0; j < 4; j++)
            gl2lds16(pB + j * rstep, &Bs[(t + j * 256) * 8]);
        pA += 64; pB += 64;
        __syncthreads();

        #pragma unroll
        for (int ks = 0; ks < 2; ks++) {
            int rc = ((ks * 4 + quad) ^ (lm & 7)) * 8;
            bf8 af[2], bfr[4];
            #pragma unroll
            for (int mi = 0; mi < 2; mi++)
                af[mi] = *(bf8*)&As[(wm + mi * 16 + lm) * 64 + rc];
            #pragma unroll
            for (int ni = 0; ni < 4; ni++)
                bfr[ni] = *(bf8*)&Bs[(wn + ni * 16 + lm) * 64 + rc];
            #pragma unroll
            for (int ni = 0; ni < 4; ni++)
            #pragma unroll
            for (int mi = 0; mi < 2; mi++)
                acc[ni][mi] = __builtin_amdgcn_mfma_f32_16x16x32_bf16(bfr[ni], af[mi], acc[ni][mi], 0, 0, 0);
        }
        __syncthreads();
    }

    f4 bv4[4];
    #pragma unroll
    for (int ni = 0; ni < 4; ni++)
        bv4[ni] = *(const f4*)&bias[n0 + wn + ni * 16 + quad * 4];
    #pragma unroll
    for (int mi = 0; mi < 2; mi++) {
        int tok = m0 + wm + mi * 16 + lm;
        float g = G[tok];
        size_t rowb = (size_t)tok * N + n0 + wn;
        #pragma unroll
        for (int ni = 0; ni < 4; ni++) {
            f4 o;
            #pragma unroll
            for (int i = 0; i < 4; i++) o[i] = g * acc[ni][mi][i] + bv4[ni][i];
            *(f4*)&out[rowb + ni * 16 + quad * 4] = o;
        }
    }
}

// ---------------------------------------------------------------------------
// Flash MFMA attention: T14 async staging + exp2-domain P + cvt_pk +
// permlane32_swap exchange. (unchanged, proven)
// ---------------------------------------------------------------------------
__global__ __launch_bounds__(256)
void attn(const ushort_t* __restrict__ Q, const ushort_t* __restrict__ K,
          const ushort_t* __restrict__ VT, ushort_t* __restrict__ Opart,
          float* __restrict__ Lw)
{
    __shared__ ushort_t Ks[64 * 72];       // [key][dim]
    __shared__ ushort_t Vt[64 * 72];       // [dim][key]

    int t = threadIdx.x, lane = t & 63, w = t >> 6;
    int l31 = lane & 31;
    uint_t hi = lane >> 5;
    int bid = blockIdx.x;
    int bh = bid & 31, qt = (bid >> 5) & 15, ks = bid >> 9;
    size_t base = (size_t)bh * 2048 * 64;

    int tok = qt * 128 + w * 32 + l31;
    const ushort_t* qp = &Q[base + (size_t)tok * 64 + hi * 8];
    bf8 qa[4];
    #pragma unroll
    for (int c = 0; c < 4; c++) qa[c] = *(const bf8*)(qp + c * 16);

    float l_part = 0.f;
    f16v o_acc[2] = {};

    int sr = t >> 3, sc = (t & 7) * 8;
    const ushort_t* kp = &K[base + (size_t)(ks * 1024 + sr) * 64 + sc];
    const ushort_t* vp = &VT[base + (size_t)sr * 2048 + ks * 1024 + sc];

    // prologue: load tile 0 into regs
    uint4 rk0 = *(const uint4*)(kp);
    uint4 rk1 = *(const uint4*)(kp + 32 * 64);
    uint4 rv0 = *(const uint4*)(vp);
    uint4 rv1 = *(const uint4*)(vp + 32 * 2048);
    kp += 64 * 64; vp += 64;

    for (int it = 0; it < 16; ++it) {
        *(uint4*)&Ks[sr * 72 + sc] = rk0;
        *(uint4*)&Ks[(sr + 32) * 72 + sc] = rk1;
        *(uint4*)&Vt[sr * 72 + sc] = rv0;
        *(uint4*)&Vt[(sr + 32) * 72 + sc] = rv1;
        __syncthreads();

        // prefetch next tile; latency hidden under this tile's compute
        rk0 = *(const uint4*)(kp);
        rk1 = *(const uint4*)(kp + 32 * 64);
        rv0 = *(const uint4*)(vp);
        rv1 = *(const uint4*)(vp + 32 * 2048);
        kp += 64 * 64; vp += 64;

        bf8 pf[4];
        #pragma unroll
        for (int kt2 = 0; kt2 < 2; kt2++) {
            f16v s = {};
            #pragma unroll
            for (int c = 0; c < 4; c++) {
                bf8 kf = *(bf8*)&Ks[(kt2 * 32 + l31) * 72 + c * 16 + hi * 8];
                s = __builtin_amdgcn_mfma_f32_32x32x16_bf16(kf, qa[c], s, 0, 0, 0);
            }
            uint_t px[4], py[4];
            #pragma unroll
            for (int g = 0; g < 4; g++) {
                float p0 = exp2_fast(s[g * 4 + 0]);
                float p1 = exp2_fast(s[g * 4 + 1]);
                float p2 = exp2_fast(s[g * 4 + 2]);
                float p3 = exp2_fast(s[g * 4 + 3]);
                l_part += (p0 + p1) + (p2 + p3);
                px[g] = cvtpk_bf16(p0, p1);
                py[g] = cvtpk_bf16(p2, p3);
            }
            #pragma unroll
            for (int cc = 0; cc < 2; cc++) {
                uint_t ax = px[2 * cc], bx = px[2 * cc + 1];
                uint_t ay = py[2 * cc], by = py[2 * cc + 1];
                pl32swap(ax, bx);    // ax = u.x (keys j0..3), bx = u.z (j4..7)
                pl32swap(ay, by);    // ay = u.y,              by = u.w
                uint4 u;
                u.x = ax; u.y = ay; u.z = bx; u.w = by;
                pf[kt2 * 2 + cc] = *(bf8*)&u;
            }
        }

        #pragma unroll
        for (int c = 0; c < 4; c++) {
            #pragma unroll
            for (int dt = 0; dt < 2; dt++) {
                bf8 vf = *(bf8*)&Vt[(dt * 32 + l31) * 72 + c * 16 + hi * 8];
                o_acc[dt] = __builtin_amdgcn_mfma_f32_32x32x16_bf16(vf, pf[c], o_acc[dt], 0, 0, 0);
            }
        }
        __syncthreads();
    }

    l_part += __shfl_xor(l_part, 32, 64);
    if (hi == 0) Lw[((size_t)ks * 32 + bh) * 2048 + tok] = l_part;

    size_t pbase = (((size_t)(ks * 32 + bh)) * 2048 + tok) * 64;
    #pragma unroll
    for (int dt = 0; dt < 2; dt++)
    #pragma unroll
    for (int g = 0; g < 4; g++) {
        int d0 = dt * 32 + g * 8 + hi * 4;
        uint2 o;
        o.x = pack2bf_fast(o_acc[dt][g * 4 + 0], o_acc[dt][g * 4 + 1]);
        o.y = pack2bf_fast(o_acc[dt][g * 4 + 2], o_acc[dt][g * 4 + 3]);
        *(uint2*)&Opart[pbase + d0] = o;
    }
}

// ---------------------------------------------------------------------------
// Fused combine + router. Grid 256 x 256: block owns 16 tokens.
// Phase 1: combine split-K partials -> LDS (padded) + global Ob.
// Phase 2 (wave 0): router MFMA from LDS (no 8MB Ob re-read), gate scalar G.
// ---------------------------------------------------------------------------
__global__ __launch_bounds__(256)
void fuseCR(const ushort_t* __restrict__ Opart, const float* __restrict__ Lw,
            const ushort_t* __restrict__ Wg, const float* __restrict__ br,
            const float* __restrict__ bs, ushort_t* __restrict__ Ob,
            float* __restrict__ G)
{
    __shared__ ushort_t Obs[16 * 1032];    // 16 tokens x 1024 dims, +8 pad
    __shared__ float rl_s[16][16];         // [head][token]
    __shared__ float Ls[16][21];

    int t = threadIdx.x;
    int tokg0 = blockIdx.x * 16;
    int b = tokg0 >> 11, st0 = tokg0 & 2047;

    // stage per-(head,token) reciprocal denominators (exactly 256 of them)
    {
        int h = t >> 4, tt = t & 15;
        size_t row = (size_t)(b * 16 + h) * 2048 + st0 + tt;
        rl_s[h][tt] = 1.f / (Lw[row] + Lw[65536 + row]);
    }
    __syncthreads();

    // combine: thread t -> token tt = t>>4, dims dc..dc+3 (uint2 per split)
    {
        int tt = t >> 4, dc = (t & 15) * 4;
        #pragma unroll 4
        for (int h = 0; h < 16; h++) {
            size_t rbase = ((size_t)(b * 16 + h) * 2048 + st0 + tt) * 64 + dc;
            uint2 p0 = *(const uint2*)&Opart[rbase];
            uint2 p1 = *(const uint2*)&Opart[4194304 + rbase];
            float rl = rl_s[h][tt];
            float v0 = (bf2f(p0.x & 0xffff) + bf2f(p1.x & 0xffff)) * rl;
            float v1 = (bf2f(p0.x >> 16)   + bf2f(p1.x >> 16))   * rl;
            float v2 = (bf2f(p0.y & 0xffff) + bf2f(p1.y & 0xffff)) * rl;
            float v3 = (bf2f(p0.y >> 16)   + bf2f(p1.y >> 16))   * rl;
            uint2 o;
            o.x = pack2bf(v0, v1);
            o.y = pack2bf(v2, v3);
            *(uint2*)&Obs[tt * 1032 + h * 64 + dc] = o;
            *(uint2*)&Ob[((size_t)(tokg0 + tt)) * 1024 + h * 64 + dc] = o;
        }
    }
    __syncthreads();

    // router (wave 0 only): logits[16 tok][17] from LDS
    if (t < 64) {
        int lm = t & 15, quad = t >> 4;
        const ushort_t* b0p = &Wg[(size_t)lm * 1024 + quad * 8];
        const ushort_t* b1p = &Wg[(size_t)(16 + lm) * 1024 + quad * 8];
        f4 acc0 = {}, acc1 = {};
        for (int k0 = 0; k0 < 1024; k0 += 32) {
            bf8 a  = *(const bf8*)&Obs[lm * 1032 + k0 + quad * 8];
            bf8 b0 = *(const bf8*)(b0p + k0);
            bf8 b1 = *(const bf8*)(b1p + k0);
            acc0 = __builtin_amdgcn_mfma_f32_16x16x32_bf16(a, b0, acc0, 0, 0, 0);
            acc1 = __builtin_amdgcn_mfma_f32_16x16x32_bf16(a, b1, acc1, 0, 0, 0);
        }
        #pragma unroll
        for (int i = 0; i < 4; i++) {
            int tl = quad * 4 + i;
            Ls[tl][lm] = acc0[i];
            if (lm == 0) Ls[tl][16] = acc1[i];
        }
        waitl0();   // intra-wave LDS ordering before cross-lane read

        if (t < 16) {
            float v[15];
            float mx = -1e30f;
            #pragma unroll
            for (int c = 0; c < 15; c++) { v[c] = Ls[t][c] + br[c]; mx = fmaxf(mx, v[c]); }
            float sum = 0.f;
            #pragma unroll
            for (int c = 0; c < 15; c++) { v[c] = __expf(v[c] - mx); sum += v[c]; }
            float inv = 1.f / sum;
            float t3 = 0.f;
            for (int r = 0; r < 3; r++) {
                int bi = 0; float bv = -1e30f;
                #pragma unroll
                for (int c = 0; c < 15; c++) if (v[c] > bv) { bv = v[c]; bi = c; }
                t3 += bv; v[bi] = -1e30f;
            }
            t3 *= inv;
            float a0 = Ls[t][15] + bs[0], a1 = Ls[t][16] + bs[1];
            float m2 = fmaxf(a0, a1);
            float e0 = __expf(a0 - m2), e1 = __expf(a1 - m2);
            G[tokg0 + t] = (2.f * e0 + 6.f * e1 * t3) / (e0 + e1);
        }
    }
}

// ---------------------------------------------------------------------------
extern "C" void kernel_launch(void* const* d_in, const int* in_sizes, int n_in,
                              void* d_out, int out_size, void* d_ws, size_t ws_size,
                              hipStream_t stream)
{
    const float* x     = (const float*)d_in[0];
    const float* Wq    = (const float*)d_in[1];
    const float* bq    = (const float*)d_in[2];
    const float* Wk    = (const float*)d_in[3];
    const float* bk    = (const float*)d_in[4];
    const float* Wv    = (const float*)d_in[5];
    const float* bv    = (const float*)d_in[6];
    const float* Wproj = (const float*)d_in[7];
    const float* bproj = (const float*)d_in[8];
    const float* Wr    = (const float*)d_in[9];
    const float* br    = (const float*)d_in[10];
    const float* Ws    = (const float*)d_in[11];
    const float* bs    = (const float*)d_in[12];
    const float* temp  = (const float*)d_in[13];
    const float* emb   = (const float*)d_in[14];

    const int M = 4096, N = 1024, Kd = 1024;

    char* ws = (char*)d_ws;
    ushort_t* Kw    = (ushort_t*)ws;                    //  8 MB [B,H,S,64]
    ushort_t* VTw   = (ushort_t*)(ws + 8388608);        //  8 MB [B,H,64,S]
    ushort_t* Qb    = (ushort_t*)(ws + 16777216);       //  8 MB Q; Ob after attn
    ushort_t* Wtp   = (ushort_t*)(ws + 25165824);       //  2 MB Wproj^T
    float*    Gw    = (float*)(ws + 27262976);          // 16 KB
    ushort_t* Wg    = (ushort_t*)(ws + 27279360);       // 64 KB
    float*    Lw    = (float*)(ws + 27344896);          // 512 KB [2][32][2048]
    ushort_t* Wt3   = (ushort_t*)(ws + 27869184);       //  6 MB (dead after QKV)
    ushort_t* xb    = (ushort_t*)(ws + 34160640);       //  8 MB (dead after QKV)
    ushort_t* Opart = (ushort_t*)(ws + 27869184);       // 16 MB, overlays Wt3+xb
    ushort_t* Ob    = Qb;                               // fuseCR writes over Q

    prep<<<8320, 256, 0, stream>>>(x, xb, Wr, Ws, Wg, Wq, Wk, Wv, Wproj,
        Wt3, Wt3 + 1048576, Wt3 + 2097152, Wtp);

    gemmQKV<<<dim3(32, 48), 256, 0, stream>>>(xb, Wt3, bq, bk, bv,
        Qb, Kw, VTw, temp, emb);

    attn<<<1024, 256, 0, stream>>>(Qb, Kw, VTw, Opart, Lw);

    fuseCR<<<256, 256, 0, stream>>>(Opart, Lw, Wg, br, bs, Ob, Gw);

    gemmP<<<dim3(64, 8), 256, 0, stream>>>(Ob, Wtp, bproj, Gw, (float*)d_out, M, N, Kd);
}